// Round 11
// baseline (533.504 us; speedup 1.0000x reference)
//
#include <hip/hip_runtime.h>
#include <hip/hip_bf16.h>

#define D_ 1024
#define H_ 2048
#define H2_ 4096
#define NE 8
#define M_ 8192
#define RBMAX 72

typedef short v8s __attribute__((ext_vector_type(8)));
typedef float v4f __attribute__((ext_vector_type(4)));

typedef const __attribute__((address_space(1))) void gvoid_t;
typedef __attribute__((address_space(3))) void svoid_t;

__device__ __forceinline__ unsigned short f2b(float f) {
    __hip_bfloat16 h = __float2bfloat16(f);
    unsigned short u;
    __builtin_memcpy(&u, &h, sizeof(u));
    return u;
}

// ---------- A. router scores + top2 + weights (NO atomics); fused x->bf16 ----------
__global__ __launch_bounds__(256) void router_score_kernel(
    const float* __restrict__ x, const float* __restrict__ Wr,
    const float* __restrict__ br, const float* __restrict__ biases,
    int* __restrict__ pick, float* __restrict__ slot_w,
    unsigned short* __restrict__ xb) {
    int wid = threadIdx.x >> 6;
    int lane = threadIdx.x & 63;
    int m = blockIdx.x * 4 + wid;
    if (m >= M_) return;
    const float4* xr = (const float4*)(x + (size_t)m * D_);
    float4 xv[4];
#pragma unroll
    for (int p = 0; p < 4; ++p) xv[p] = xr[p * 64 + lane];
    ushort4* xbr = (ushort4*)(xb + (size_t)m * D_);
#pragma unroll
    for (int p = 0; p < 4; ++p) {
        ushort4 o;
        o.x = f2b(xv[p].x); o.y = f2b(xv[p].y); o.z = f2b(xv[p].z); o.w = f2b(xv[p].w);
        xbr[p * 64 + lane] = o;
    }
    float s[NE];
#pragma unroll
    for (int n = 0; n < NE; ++n) {
        const float4* wr = (const float4*)(Wr + (size_t)n * D_);
        float acc = 0.f;
#pragma unroll
        for (int p = 0; p < 4; ++p) {
            float4 w4 = wr[p * 64 + lane];
            acc += xv[p].x * w4.x + xv[p].y * w4.y + xv[p].z * w4.z + xv[p].w * w4.w;
        }
#pragma unroll
        for (int off = 32; off; off >>= 1) acc += __shfl_xor(acc, off, 64);
        s[n] = acc + br[n];
    }
    if (lane == 0) {
        float t[NE];
#pragma unroll
        for (int n = 0; n < NE; ++n) t[n] = s[n] + biases[n];
        int i0 = 0;
#pragma unroll
        for (int n = 1; n < NE; ++n) if (t[n] > t[i0]) i0 = n;
        int i1 = -1;
#pragma unroll
        for (int n = 0; n < NE; ++n) {
            if (n == i0) continue;
            if (i1 < 0 || t[n] > t[i1]) i1 = n;
        }
        float mx = fmaxf(s[i0], s[i1]);
        float e0 = expf(s[i0] - mx), e1 = expf(s[i1] - mx);
        float inv = 1.f / (e0 + e1);
        pick[m] = i0 | (i1 << 4);
        slot_w[m * 2] = e0 * inv;
        slot_w[m * 2 + 1] = e1 * inv;
    }
}

// ---------- B. per-block histogram over picks (LDS atomics only) ----------
__global__ __launch_bounds__(256) void hist_kernel(const int* __restrict__ pick,
                                                   int* __restrict__ blkcnt) {
    __shared__ int h[NE];
    int t = threadIdx.x;
    if (t < NE) h[t] = 0;
    __syncthreads();
    int idx = blockIdx.x * 256 + t;
    int e = (pick[idx >> 1] >> ((idx & 1) * 4)) & 15;
    atomicAdd(&h[e], 1);
    __syncthreads();
    if (t < NE) blkcnt[blockIdx.x * NE + t] = h[t];
}

// ---------- C. scan: per-expert block offsets + cnt + bp ----------
__global__ void scan_kernel(const int* __restrict__ blkcnt, int* __restrict__ blkoff,
                            int* __restrict__ cnt, int* __restrict__ bp) {
    int e = threadIdx.x;
    if (e < NE) {
        int run = 0;
        for (int b = 0; b < 64; ++b) {
            blkoff[b * NE + e] = run;
            run += blkcnt[b * NE + e];
        }
        cnt[e] = run;
    }
    __syncthreads();
    if (e == 0) {
        int b = 0, r = 0;
        for (int n = 0; n < NE; ++n) {
            bp[n] = b; bp[16 + n] = r;
            b += ((cnt[n] + 255) / 256) * 256;
            r += cnt[n];
        }
        bp[NE] = b; bp[16 + NE] = r;
    }
}

// ---------- D. scatter: ballot-ranked deterministic compaction ----------
__global__ __launch_bounds__(256) void scatter_kernel(
    const int* __restrict__ pick, const int* __restrict__ blkoff,
    int* __restrict__ perm, int* __restrict__ slot_idx) {
    __shared__ int wvcnt[4 * NE];
    int t = threadIdx.x, lane = t & 63, w = t >> 6;
    int idx = blockIdx.x * 256 + t;
    int m = idx >> 1, sl = idx & 1;
    int e = (pick[m] >> (sl * 4)) & 15;
    unsigned long long ltm = (1ull << lane) - 1;
    int my = 0;
#pragma unroll
    for (int ee = 0; ee < NE; ++ee) {
        unsigned long long mask = __ballot(e == ee);
        if (ee == e) my = __popcll(mask & ltm);
        if (lane == ee) wvcnt[w * NE + ee] = __popcll(mask);
    }
    __syncthreads();
    int off = blkoff[blockIdx.x * NE + e] + my;
    for (int w2 = 0; w2 < w; ++w2) off += wvcnt[w2 * NE + e];
    perm[e * M_ + off] = m;
    slot_idx[m * 2 + sl] = (e << 13) | off;
}

// ---------- pack W1 ----------
__global__ __launch_bounds__(256) void pack_w1_kernel(const float* __restrict__ Wl1,
                                                      unsigned short* __restrict__ W1P) {
    int jb = blockIdx.x, t = blockIdx.y, e = blockIdx.z;
    int tid = threadIdx.x;
    int lr = tid;
    int q = lr >> 7;
    int h = jb * 128 + (tid & 127);
    size_t srcb = ((size_t)e * D_ + t * 64) * H2_ + (size_t)q * H_ + h;
    unsigned short* dst = W1P + ((((size_t)(e * 16 + jb) * 16 + t) * 2 + q) << 13) + ((lr & 127) * 8) * 8;
    int sw = lr & 7;
    v8s v;
#pragma unroll 2
    for (int g = 0; g < 8; ++g) {
#pragma unroll
        for (int j = 0; j < 8; ++j) {
            float f = Wl1[srcb + (size_t)(g * 8 + j) * H2_];
            v[j] = (short)f2b(f);
        }
        *(v8s*)(dst + (size_t)(g ^ sw) * 8) = v;
    }
}

// ---------- pack W2 ----------
__global__ __launch_bounds__(256) void pack_w2_kernel(const float* __restrict__ Wl2,
                                                      unsigned short* __restrict__ W2P) {
    int jb = blockIdx.x, t = blockIdx.y, e = blockIdx.z;
    int tid = threadIdx.x;
    int row = tid & 127, half = tid >> 7;
    int col = jb * 128 + row;
    unsigned short* dst = W2P + ((size_t)(e * 8 + jb) * 32 + t) * 8192 + row * 64;
#pragma unroll
    for (int gg = 0; gg < 4; ++gg) {
        int g = half * 4 + gg;
        int kgrp = g ^ (row & 7);
        v8s v;
#pragma unroll
        for (int j = 0; j < 8; ++j) {
            float f = Wl2[((size_t)e * H_ + t * 64 + kgrp * 8 + j) * D_ + col];
            v[j] = (short)f2b(f);
        }
        *(v8s*)(dst + g * 8) = v;
    }
}

// ---------- staging macros ----------
#define GLDS(src, dst) __builtin_amdgcn_global_load_lds((gvoid_t*)(src), (svoid_t*)(dst), 16, 0, 0)
#define STB_(dstbase, t, q) { const unsigned short* s_ = Bsrc + (((size_t)(t) * 2 + (q)) << 13) + tid * 8; \
    GLDS(s_, (dstbase) + (q) * 8192 + tid * 8); \
    GLDS(s_ + 4096, (dstbase) + (q) * 8192 + 4096 + tid * 8); }
#define STA_X(dstbase, t, q) { \
    GLDS(aptr[q][0] + (size_t)(t) * 64, (dstbase) + (q) * 8192 + tid * 8); \
    GLDS(aptr[q][1] + (size_t)(t) * 64, (dstbase) + (q) * 8192 + 4096 + tid * 8); }

// register-fragment loads (compiler-visible -> counted lgkmcnt, true pipe overlap)
#define LDA1(DST, Ab, QM) { _Pragma("unroll") for (int i_ = 0; i_ < 4; ++i_) { \
    const unsigned short* ar_ = (Ab) + ((QM) * 128 + wm * 64 + i_ * 16 + fr) * 64; \
    DST[i_][0] = *(const v8s*)(ar_ + s0); DST[i_][1] = *(const v8s*)(ar_ + s1); } }
#define LDB1(DST, Bb, QN) { _Pragma("unroll") for (int n_ = 0; n_ < 2; ++n_) { \
    const unsigned short* br_ = (Bb) + ((QN) * 128 + wn * 32 + n_ * 16 + fr) * 64; \
    DST[n_][0] = *(const v8s*)(br_ + s0); DST[n_][1] = *(const v8s*)(br_ + s1); } }
#define LDB2(DST, Bp_) { _Pragma("unroll") for (int n_ = 0; n_ < 2; ++n_) { \
    const unsigned short* br_ = (Bp_) + (wn * 32 + n_ * 16 + fr) * 64; \
    DST[n_][0] = *(const v8s*)(br_ + s0); DST[n_][1] = *(const v8s*)(br_ + s1); } }

// MFMA burst + single end-of-phase sync: lgkmcnt(0) (all reads retired for all
// waves at barrier) + counted vmcnt (stages >=2 phases old visible after barrier)
#define MM1(AS, BS, QM, QN) \
    __builtin_amdgcn_sched_barrier(0); \
    __builtin_amdgcn_s_setprio(1); \
    _Pragma("unroll") for (int kk_ = 0; kk_ < 2; ++kk_) \
        _Pragma("unroll") for (int i_ = 0; i_ < 4; ++i_) \
            _Pragma("unroll") for (int n_ = 0; n_ < 2; ++n_) \
                acc[(QM) * 4 + i_][(QN) * 2 + n_] = __builtin_amdgcn_mfma_f32_16x16x32_bf16( \
                    AS[i_][kk_], BS[n_][kk_], acc[(QM) * 4 + i_][(QN) * 2 + n_], 0, 0, 0); \
    __builtin_amdgcn_s_setprio(0); \
    __builtin_amdgcn_sched_barrier(0); \
    asm volatile("s_waitcnt vmcnt(4) lgkmcnt(0)" ::: "memory"); \
    __builtin_amdgcn_s_barrier();

#define MM2(AS, BS, QM) \
    __builtin_amdgcn_sched_barrier(0); \
    __builtin_amdgcn_s_setprio(1); \
    _Pragma("unroll") for (int kk_ = 0; kk_ < 2; ++kk_) \
        _Pragma("unroll") for (int i_ = 0; i_ < 4; ++i_) \
            _Pragma("unroll") for (int n_ = 0; n_ < 2; ++n_) \
                acc[(QM) * 4 + i_][n_] = __builtin_amdgcn_mfma_f32_16x16x32_bf16( \
                    AS[i_][kk_], BS[n_][kk_], acc[(QM) * 4 + i_][n_], 0, 0, 0); \
    __builtin_amdgcn_s_setprio(0); \
    __builtin_amdgcn_sched_barrier(0); \
    asm volatile("s_waitcnt vmcnt(3) lgkmcnt(0)" ::: "memory"); \
    __builtin_amdgcn_s_barrier();

// ---------- GEMM1: 256x256, 8-phase snake, reads lead MFMA by one phase ----------
__global__ __launch_bounds__(512, 2) void gemm1_kernel(
    const unsigned short* __restrict__ xb, const unsigned short* __restrict__ Bpack,
    const float* __restrict__ bias, const int* __restrict__ cnt, const int* __restrict__ bp,
    const int* __restrict__ perm, unsigned short* __restrict__ actP) {
    constexpr int NT = 16;
    int p = blockIdx.x;
    int tm = (p >> 3) & 31;
    int pid = (p & 7) + ((p >> 8) << 3);
    int e = pid >> 4;
    int jb = pid & 15;
    int cn = cnt[e];
    if (tm * 256 >= cn) return;
    int rb = (bp[e] >> 8) + tm;

    __shared__ __align__(16) unsigned short SH[66560];
    unsigned short* As0 = SH;
    unsigned short* As1 = SH + 16384;
    unsigned short* Bs0 = SH + 32768;
    unsigned short* Bs1 = SH + 49152;

    int tid = threadIdx.x, lane = tid & 63, wid = tid >> 6;
    int wm = wid >> 2, wn = wid & 3;
    int fr = lane & 15, fg = lane >> 4;
    int swz = fr & 7;
    int s0 = (fg ^ swz) * 8;
    int s1 = ((4 + fg) ^ swz) * 8;

    int kgs = tid & 7;
    const unsigned short* aptr[2][2];
#pragma unroll
    for (int q = 0; q < 2; ++q)
#pragma unroll
        for (int h = 0; h < 2; ++h) {
            int lr = q * 128 + h * 64 + (tid >> 3);
            int r = ((lr >> 6) & 1) * 128 + ((lr >> 7) & 1) * 64 + (lr & 63);
            int rl = min(tm * 256 + r, cn - 1);
            int tok = perm[e * M_ + rl];
            aptr[q][h] = xb + (size_t)tok * D_ + ((kgs ^ (lr & 7)) << 3);
        }

    const unsigned short* Bsrc = Bpack + (((size_t)(e * 16 + jb) * NT) << 14);

    v4f acc[8][4] = {};
    v8s a0_[4][2], a1_[4][2];
    v8s b0_[2][2], b1_[2][2];

    // prologue: stage tile0 full + tile1 (As1.q0, Bs1.q1); drain; lead-load ph1 frags
    STA_X(As0, 0, 0); STB_(Bs0, 0, 1); STA_X(As0, 0, 1); STB_(Bs0, 0, 0);
    STA_X(As1, 1, 0); STB_(Bs1, 1, 1);
    asm volatile("s_waitcnt vmcnt(0)" ::: "memory");
    __builtin_amdgcn_s_barrier();
    LDA1(a0_, As0, 0); LDB1(b0_, Bs0, 0);

    for (int i2 = 0; i2 < NT / 2; ++i2) {
        int T1 = 2 * i2 + 1;
        int T2c = min(2 * i2 + 2, NT - 1);
        int T3c = min(2 * i2 + 3, NT - 1);
        // ph1 (use a0,b0 @ As0/Bs0 Q00): lead b1<-Bs0.q1; stage Bs1.q0[T1]
        LDB1(b1_, Bs0, 1); STB_(Bs1, T1, 0); MM1(a0_, b0_, 0, 0);
        // ph2 (a0,b1 @ Q01): lead a1<-As0.q1; stage As1.q1[T1]
        LDA1(a1_, As0, 1); STA_X(As1, T1, 1); MM1(a0_, b1_, 0, 1);
        // ph3 (a1,b1 @ Q11): lead b0<-Bs0.q0; stage As0.q0[T2c]
        LDB1(b0_, Bs0, 0); STA_X(As0, T2c, 0); MM1(a1_, b1_, 1, 1);
        // ph4 (a1,b0 @ Q10): leads a0<-As1.q0, b1<-Bs1.q0; stage Bs0.q1[T2c]
        LDA1(a0_, As1, 0); LDB1(b1_, Bs1, 0); STB_(Bs0, T2c, 1); MM1(a1_, b0_, 1, 0);
        // ph5 (a0,b1 @ As1/Bs1 Q00): lead b0<-Bs1.q1; stage Bs0.q0[T2c]
        LDB1(b0_, Bs1, 1); STB_(Bs0, T2c, 0); MM1(a0_, b1_, 0, 0);
        // ph6 (a0,b0 @ Q01): lead a1<-As1.q1; stage As0.q1[T2c]
        LDA1(a1_, As1, 1); STA_X(As0, T2c, 1); MM1(a0_, b0_, 0, 1);
        // ph7 (a1,b0 @ Q11): lead b1<-Bs1.q0; stage As1.q0[T3c]
        LDB1(b1_, Bs1, 0); STA_X(As1, T3c, 0); MM1(a1_, b0_, 1, 1);
        // ph8 (a1,b1 @ Q10): leads a0<-As0.q0, b0<-Bs0.q0 (next T0); stage Bs1.q1[T3c]
        LDA1(a0_, As0, 0); LDB1(b0_, Bs0, 0); STB_(Bs1, T3c, 1); MM1(a1_, b1_, 1, 0);
    }
    asm volatile("s_waitcnt vmcnt(0)" ::: "memory");
    __syncthreads();

    // epilogue: silu(a)*b -> LDS [256][136] -> packed actP units
    unsigned short* actl = SH;
    int hl0 = wn * 32 + fr, hl1 = wn * 32 + 16 + fr;
    float ba0 = bias[e * H2_ + jb * 128 + hl0];
    float bb0 = bias[e * H2_ + H_ + jb * 128 + hl0];
    float ba1 = bias[e * H2_ + jb * 128 + hl1];
    float bb1 = bias[e * H2_ + H_ + jb * 128 + hl1];
#pragma unroll
    for (int I = 0; I < 8; ++I) {
        int r0 = wm * 128 + (I >> 2) * 64 + (I & 3) * 16 + fg * 4;
#pragma unroll
        for (int rr = 0; rr < 4; ++rr) {
            float a0 = acc[I][0][rr] + ba0, b0 = acc[I][2][rr] + bb0;
            float a1 = acc[I][1][rr] + ba1, b1 = acc[I][3][rr] + bb1;
            actl[(r0 + rr) * 136 + hl0] = f2b(a0 / (1.f + __expf(-a0)) * b0);
            actl[(r0 + rr) * 136 + hl1] = f2b(a1 / (1.f + __expf(-a1)) * b1);
        }
    }
    __syncthreads();
#pragma unroll
    for (int c8 = 0; c8 < 8; ++c8) {
        int cid = c8 * 512 + tid;
        int t2l = cid >> 11, rem = cid & 2047;
        int q = rem >> 10, s = rem & 1023;
        int lr = q * 128 + (s >> 3);
        int g = (s & 7) ^ (lr & 7);
        int r = ((lr >> 6) & 1) * 128 + (lr >> 7) * 64 + (lr & 63);
        v8s v = *(const v8s*)(actl + r * 136 + t2l * 64 + g * 8);
        *(v8s*)(actP + ((((size_t)rb * 32 + jb * 2 + t2l) * 2 + q) << 13) + s * 8) = v;
    }
}

// ---------- GEMM2: 256x128, 4-phase, triple-buffered B, reads lead by one phase ----------
#define STAH2(dst, t, q) { const unsigned short* s_ = Asrc + (((size_t)(t) * 2 + (q)) << 13) + tid * 8; \
    GLDS(s_, (dst) + (q) * 8192 + tid * 8); \
    GLDS(s_ + 4096, (dst) + (q) * 8192 + 4096 + tid * 8); }
#define STBH2(dst, t, h) { const unsigned short* s_ = Bsrc + ((size_t)(t) * 8192) + (h) * 4096 + tid * 8; \
    GLDS(s_, (dst) + (h) * 4096 + tid * 8); }

__global__ __launch_bounds__(512, 2) void gemm2_kernel(
    const unsigned short* __restrict__ actP, const unsigned short* __restrict__ W2P,
    const float* __restrict__ bl2, const int* __restrict__ cnt, const int* __restrict__ bp,
    float* __restrict__ y) {
    constexpr int NT = 32;
    int p = blockIdx.x;
    int tm = (p >> 3) & 31;
    int pid = (p & 7) + ((p >> 8) << 3);
    int e = pid >> 3;
    int jb = pid & 7;
    int cn = cnt[e];
    if (tm * 256 >= cn) return;
    int rb = (bp[e] >> 8) + tm;

    __shared__ __align__(16) unsigned short SH[57344];
    unsigned short* As0 = SH;
    unsigned short* As1 = SH + 16384;
    unsigned short* Bb0 = SH + 32768;
    unsigned short* Bb1 = SH + 40960;
    unsigned short* Bb2 = SH + 49152;

    int tid = threadIdx.x, lane = tid & 63, wid = tid >> 6;
    int wm = wid >> 2, wn = wid & 3;
    int fr = lane & 15, fg = lane >> 4;
    int swz = fr & 7;
    int s0 = (fg ^ swz) * 8;
    int s1 = ((4 + fg) ^ swz) * 8;

    const unsigned short* Asrc = actP + ((size_t)rb << 19);
    const unsigned short* Bsrc = W2P + ((size_t)(e * 8 + jb) * 32) * 8192;

    v4f acc[8][2] = {};
    v8s a0_[4][2], a1_[4][2];
    v8s b0_[2][2], b1_[2][2];

    STAH2(As0, 0, 0); STAH2(As0, 0, 1);
    STBH2(Bb0, 0, 0); STBH2(Bb0, 0, 1);
    STAH2(As1, 1, 0);
    STBH2(Bb1, 1, 0); STBH2(Bb1, 1, 1);
    asm volatile("s_waitcnt vmcnt(0)" ::: "memory");
    __builtin_amdgcn_s_barrier();

    unsigned short* Bc0 = Bb0;
    unsigned short* Bc1 = Bb1;
    unsigned short* Bn = Bb2;
    LDA1(a0_, As0, 0); LDB2(b0_, Bc0);

    for (int i2 = 0; i2 < NT / 2; ++i2) {
        int T1 = 2 * i2 + 1;
        int T2 = min(2 * i2 + 2, NT - 1);
        int T3 = min(2 * i2 + 3, NT - 1);
        // ph1 (a0,b0 @ As0.q0): lead a1<-As0.q1; stage As1.q1[T1], Bn.h0[T2]
        LDA1(a1_, As0, 1); STAH2(As1, T1, 1); STBH2(Bn, T2, 0); MM2(a0_, b0_, 0);
        // ph2 (a1,b0 @ As0.q1): leads a0<-As1.q0, b1<-Bc1; stage As0.q0[T2], Bn.h1[T2]
        LDA1(a0_, As1, 0); LDB2(b1_, Bc1); STAH2(As0, T2, 0); STBH2(Bn, T2, 1); MM2(a1_, b0_, 1);
        // ph3 (a0,b1 @ As1.q0): lead a1<-As1.q1; stage As0.q1[T2], Bc0.h0[T3]
        LDA1(a1_, As1, 1); STAH2(As0, T2, 1); STBH2(Bc0, T3, 0); MM2(a0_, b1_, 0);
        // ph4 (a1,b1 @ As1.q1): leads a0<-As0.q0 (T2), b0<-Bn (T2, = next Bc0); stage As1.q0[T3], Bc0.h1[T3]
        LDA1(a0_, As0, 0); LDB2(b0_, Bn); STAH2(As1, T3, 0); STBH2(Bc0, T3, 1); MM2(a1_, b1_, 1);
        unsigned short* oB0 = Bc0;
        Bc0 = Bn; Bn = Bc1; Bc1 = oB0;
    }
    asm volatile("s_waitcnt vmcnt(0)" ::: "memory");
    __syncthreads();

    // epilogue: +bl2 -> LDS f32 [128][132] -> coalesced y rows
    float* yl = (float*)SH;
    int bsr = bp[16 + e];
    float b2_0 = bl2[e * D_ + jb * 128 + wn * 32 + fr];
    float b2_1 = bl2[e * D_ + jb * 128 + wn * 32 + 16 + fr];
#pragma unroll
    for (int wmp = 0; wmp < 2; ++wmp) {
        if (wm == wmp) {
#pragma unroll
            for (int I = 0; I < 8; ++I) {
                int r0 = (I >> 2) * 64 + (I & 3) * 16 + fg * 4;
#pragma unroll
                for (int rr = 0; rr < 4; ++rr) {
                    yl[(r0 + rr) * 132 + wn * 32 + fr] = acc[I][0][rr] + b2_0;
                    yl[(r0 + rr) * 132 + wn * 32 + 16 + fr] = acc[I][1][rr] + b2_1;
                }
            }
        }
        __syncthreads();
#pragma unroll
        for (int f = 0; f < 8; ++f) {
            int fid = f * 512 + tid;
            int row = fid >> 5, c4 = fid & 31;
            int rp = tm * 256 + wmp * 128 + row;
            if (rp < cn) {
                float4 v = *(const float4*)(yl + row * 132 + c4 * 4);
                *(float4*)(y + (size_t)(bsr + rp) * D_ + jb * 128 + c4 * 4) = v;
            }
        }
        __syncthreads();
    }
}

// ---------- combine ----------
__global__ __launch_bounds__(256) void combine_kernel(
    const float* __restrict__ y, const int* __restrict__ slot_idx,
    const float* __restrict__ slot_w, const int* __restrict__ bp,
    float* __restrict__ out) {
    int m = blockIdx.x * 4 + (threadIdx.x >> 6);
    int t2 = threadIdx.x & 63;
    int i0 = slot_idx[m * 2], i1 = slot_idx[m * 2 + 1];
    float w0 = slot_w[m * 2], w1 = slot_w[m * 2 + 1];
    const float4* y0 = (const float4*)(y + (size_t)(bp[16 + (i0 >> 13)] + (i0 & (M_ - 1))) * D_);
    const float4* y1 = (const float4*)(y + (size_t)(bp[16 + (i1 >> 13)] + (i1 & (M_ - 1))) * D_);
    float4* o = (float4*)(out + (size_t)m * D_);
#pragma unroll
    for (int k = 0; k < 4; ++k) {
        int idx = k * 64 + t2;
        float4 a = y0[idx], b = y1[idx];
        float4 r;
        r.x = w0 * a.x + w1 * b.x;
        r.y = w0 * a.y + w1 * b.y;
        r.z = w0 * a.z + w1 * b.z;
        r.w = w0 * a.w + w1 * b.w;
        o[idx] = r;
    }
}

__global__ void ws_fail_kernel(float* __restrict__ out) {
    if (threadIdx.x == 0 && blockIdx.x == 0) out[0] = 1e30f;
}

extern "C" void kernel_launch(void* const* d_in, const int* in_sizes, int n_in,
                              void* d_out, int out_size, void* d_ws, size_t ws_size,
                              hipStream_t stream) {
    const float* x = (const float*)d_in[0];
    const float* Wr = (const float*)d_in[1];
    const float* br = (const float*)d_in[2];
    const float* Wl1 = (const float*)d_in[3];
    const float* bl1 = (const float*)d_in[4];
    const float* Wl2 = (const float*)d_in[5];
    const float* bl2 = (const float*)d_in[6];
    const float* biases = (const float*)d_in[7];
    float* out = (float*)d_out;

    char* ws = (char*)d_ws;
    size_t off = 0;
    auto alloc = [&](size_t bytes) {
        char* p = ws + off;
        off += (bytes + 255) & ~(size_t)255;
        return p;
    };
    unsigned short* W1P = (unsigned short*)alloc((size_t)NE * 16 * 16 * 2 * 8192 * 2);  // 64 MB
    unsigned short* W2P = (unsigned short*)alloc((size_t)NE * 8 * 32 * 8192 * 2);       // 32 MB
    unsigned short* xb = (unsigned short*)alloc((size_t)M_ * D_ * 2);                   // 16 MB
    unsigned short* actP = (unsigned short*)alloc((size_t)RBMAX * 32 * 2 * 8192 * 2);   // 72 MB
    int* perm = (int*)alloc((size_t)NE * M_ * 4);
    int* slot_idx = (int*)alloc((size_t)M_ * 2 * 4);
    float* slot_w = (float*)alloc((size_t)M_ * 2 * 4);
    int* pick = (int*)alloc((size_t)M_ * 4);
    int* blkcnt = (int*)alloc(64 * NE * 4);
    int* blkoff = (int*)alloc(64 * NE * 4);
    int* cnt = (int*)alloc(256);
    int* bp = (int*)alloc(256);
    float* y = (float*)W1P;  // W1P dead after gemm1
    if (ws_size < off) {
        ws_fail_kernel<<<1, 64, 0, stream>>>(out);
        return;
    }

    pack_w1_kernel<<<dim3(16, 16, NE), 256, 0, stream>>>(Wl1, W1P);
    pack_w2_kernel<<<dim3(8, 32, NE), 256, 0, stream>>>(Wl2, W2P);
    router_score_kernel<<<M_ / 4, 256, 0, stream>>>(x, Wr, br, biases, pick, slot_w, xb);
    hist_kernel<<<64, 256, 0, stream>>>(pick, blkcnt);
    scan_kernel<<<1, 64, 0, stream>>>(blkcnt, blkoff, cnt, bp);
    scatter_kernel<<<64, 256, 0, stream>>>(pick, blkoff, perm, slot_idx);
    gemm1_kernel<<<32 * 16 * NE, 512, 0, stream>>>(xb, W1P, bl1, cnt, bp, perm, actP);
    gemm2_kernel<<<32 * 8 * NE, 512, 0, stream>>>(actP, W2P, bl2, cnt, bp, y);
    combine_kernel<<<M_ / 4, 256, 0, stream>>>(y, slot_idx, slot_w, bp, out);
}

// Round 12
// 406.974 us; speedup vs baseline: 1.3109x; 1.3109x over previous
//
#include <hip/hip_runtime.h>
#include <hip/hip_bf16.h>

#define D_ 1024
#define H_ 2048
#define H2_ 4096
#define NE 8
#define M_ 8192
#define RBMAX 72

typedef short v8s __attribute__((ext_vector_type(8)));
typedef float v4f __attribute__((ext_vector_type(4)));

typedef const __attribute__((address_space(1))) void gvoid_t;
typedef __attribute__((address_space(3))) void svoid_t;

__device__ __forceinline__ unsigned short f2b(float f) {
    __hip_bfloat16 h = __float2bfloat16(f);
    unsigned short u;
    __builtin_memcpy(&u, &h, sizeof(u));
    return u;
}

// ---------- A. router scores + top2 + weights (NO atomics); fused x->bf16 ----------
__global__ __launch_bounds__(256) void router_score_kernel(
    const float* __restrict__ x, const float* __restrict__ Wr,
    const float* __restrict__ br, const float* __restrict__ biases,
    int* __restrict__ pick, float* __restrict__ slot_w,
    unsigned short* __restrict__ xb) {
    int wid = threadIdx.x >> 6;
    int lane = threadIdx.x & 63;
    int m = blockIdx.x * 4 + wid;
    if (m >= M_) return;
    const float4* xr = (const float4*)(x + (size_t)m * D_);
    float4 xv[4];
#pragma unroll
    for (int p = 0; p < 4; ++p) xv[p] = xr[p * 64 + lane];
    ushort4* xbr = (ushort4*)(xb + (size_t)m * D_);
#pragma unroll
    for (int p = 0; p < 4; ++p) {
        ushort4 o;
        o.x = f2b(xv[p].x); o.y = f2b(xv[p].y); o.z = f2b(xv[p].z); o.w = f2b(xv[p].w);
        xbr[p * 64 + lane] = o;
    }
    float s[NE];
#pragma unroll
    for (int n = 0; n < NE; ++n) {
        const float4* wr = (const float4*)(Wr + (size_t)n * D_);
        float acc = 0.f;
#pragma unroll
        for (int p = 0; p < 4; ++p) {
            float4 w4 = wr[p * 64 + lane];
            acc += xv[p].x * w4.x + xv[p].y * w4.y + xv[p].z * w4.z + xv[p].w * w4.w;
        }
#pragma unroll
        for (int off = 32; off; off >>= 1) acc += __shfl_xor(acc, off, 64);
        s[n] = acc + br[n];
    }
    if (lane == 0) {
        float t[NE];
#pragma unroll
        for (int n = 0; n < NE; ++n) t[n] = s[n] + biases[n];
        int i0 = 0;
#pragma unroll
        for (int n = 1; n < NE; ++n) if (t[n] > t[i0]) i0 = n;
        int i1 = -1;
#pragma unroll
        for (int n = 0; n < NE; ++n) {
            if (n == i0) continue;
            if (i1 < 0 || t[n] > t[i1]) i1 = n;
        }
        float mx = fmaxf(s[i0], s[i1]);
        float e0 = expf(s[i0] - mx), e1 = expf(s[i1] - mx);
        float inv = 1.f / (e0 + e1);
        pick[m] = i0 | (i1 << 4);
        slot_w[m * 2] = e0 * inv;
        slot_w[m * 2 + 1] = e1 * inv;
    }
}

// ---------- B. per-block histogram over picks (LDS atomics only) ----------
__global__ __launch_bounds__(256) void hist_kernel(const int* __restrict__ pick,
                                                   int* __restrict__ blkcnt) {
    __shared__ int h[NE];
    int t = threadIdx.x;
    if (t < NE) h[t] = 0;
    __syncthreads();
    int idx = blockIdx.x * 256 + t;
    int e = (pick[idx >> 1] >> ((idx & 1) * 4)) & 15;
    atomicAdd(&h[e], 1);
    __syncthreads();
    if (t < NE) blkcnt[blockIdx.x * NE + t] = h[t];
}

// ---------- C. scan: per-expert block offsets + cnt + bp ----------
__global__ void scan_kernel(const int* __restrict__ blkcnt, int* __restrict__ blkoff,
                            int* __restrict__ cnt, int* __restrict__ bp) {
    int e = threadIdx.x;
    if (e < NE) {
        int run = 0;
        for (int b = 0; b < 64; ++b) {
            blkoff[b * NE + e] = run;
            run += blkcnt[b * NE + e];
        }
        cnt[e] = run;
    }
    __syncthreads();
    if (e == 0) {
        int b = 0, r = 0;
        for (int n = 0; n < NE; ++n) {
            bp[n] = b; bp[16 + n] = r;
            b += ((cnt[n] + 255) / 256) * 256;
            r += cnt[n];
        }
        bp[NE] = b; bp[16 + NE] = r;
    }
}

// ---------- D. scatter: ballot-ranked deterministic compaction ----------
__global__ __launch_bounds__(256) void scatter_kernel(
    const int* __restrict__ pick, const int* __restrict__ blkoff,
    int* __restrict__ perm, int* __restrict__ slot_idx) {
    __shared__ int wvcnt[4 * NE];
    int t = threadIdx.x, lane = t & 63, w = t >> 6;
    int idx = blockIdx.x * 256 + t;
    int m = idx >> 1, sl = idx & 1;
    int e = (pick[m] >> (sl * 4)) & 15;
    unsigned long long ltm = (1ull << lane) - 1;
    int my = 0;
#pragma unroll
    for (int ee = 0; ee < NE; ++ee) {
        unsigned long long mask = __ballot(e == ee);
        if (ee == e) my = __popcll(mask & ltm);
        if (lane == ee) wvcnt[w * NE + ee] = __popcll(mask);
    }
    __syncthreads();
    int off = blkoff[blockIdx.x * NE + e] + my;
    for (int w2 = 0; w2 < w; ++w2) off += wvcnt[w2 * NE + e];
    perm[e * M_ + off] = m;
    slot_idx[m * 2 + sl] = (e << 13) | off;
}

// ---------- pack W1 ----------
__global__ __launch_bounds__(256) void pack_w1_kernel(const float* __restrict__ Wl1,
                                                      unsigned short* __restrict__ W1P) {
    int jb = blockIdx.x, t = blockIdx.y, e = blockIdx.z;
    int tid = threadIdx.x;
    int lr = tid;
    int q = lr >> 7;
    int h = jb * 128 + (tid & 127);
    size_t srcb = ((size_t)e * D_ + t * 64) * H2_ + (size_t)q * H_ + h;
    unsigned short* dst = W1P + ((((size_t)(e * 16 + jb) * 16 + t) * 2 + q) << 13) + ((lr & 127) * 8) * 8;
    int sw = lr & 7;
    v8s v;
#pragma unroll 2
    for (int g = 0; g < 8; ++g) {
#pragma unroll
        for (int j = 0; j < 8; ++j) {
            float f = Wl1[srcb + (size_t)(g * 8 + j) * H2_];
            v[j] = (short)f2b(f);
        }
        *(v8s*)(dst + (size_t)(g ^ sw) * 8) = v;
    }
}

// ---------- pack W2 ----------
__global__ __launch_bounds__(256) void pack_w2_kernel(const float* __restrict__ Wl2,
                                                      unsigned short* __restrict__ W2P) {
    int jb = blockIdx.x, t = blockIdx.y, e = blockIdx.z;
    int tid = threadIdx.x;
    int row = tid & 127, half = tid >> 7;
    int col = jb * 128 + row;
    unsigned short* dst = W2P + ((size_t)(e * 8 + jb) * 32 + t) * 8192 + row * 64;
#pragma unroll
    for (int gg = 0; gg < 4; ++gg) {
        int g = half * 4 + gg;
        int kgrp = g ^ (row & 7);
        v8s v;
#pragma unroll
        for (int j = 0; j < 8; ++j) {
            float f = Wl2[((size_t)e * H_ + t * 64 + kgrp * 8 + j) * D_ + col];
            v[j] = (short)f2b(f);
        }
        *(v8s*)(dst + g * 8) = v;
    }
}

// ---------- staging macros ----------
#define GLDS(src, dst) __builtin_amdgcn_global_load_lds((gvoid_t*)(src), (svoid_t*)(dst), 16, 0, 0)
#define STB_(dstbase, t, q) { const unsigned short* s_ = Bsrc + (((size_t)(t) * 2 + (q)) << 13) + tid * 8; \
    GLDS(s_, (dstbase) + (q) * 8192 + tid * 8); \
    GLDS(s_ + 4096, (dstbase) + (q) * 8192 + 4096 + tid * 8); }
#define STA_X(dstbase, t, q) { \
    GLDS(aptr[q][0] + (size_t)(t) * 64, (dstbase) + (q) * 8192 + tid * 8); \
    GLDS(aptr[q][1] + (size_t)(t) * 64, (dstbase) + (q) * 8192 + 4096 + tid * 8); }

// ---------- GEMM1 PHASE: ONE barrier per phase. reads/stage/MFMA freely
// schedulable within the phase (compiler counted-lgkm interleave); pinned at
// phase end by sched_barrier + [vmcnt] + s_barrier + sched_barrier.
// Hazard distances re-verified: every stage->read and read->overwrite pair is
// separated by >=1 end barrier; vmcnt(4) at ph4/ph8 retires exactly the units
// needed 1+ phase before their first read.
#define PHASE(Ab, Bb, QM, QN, LA, LB, STAGE_STMT, VM4) do { \
    if (LA) { _Pragma("unroll") for (int i_ = 0; i_ < 4; ++i_) { \
        const unsigned short* ar_ = (Ab) + ((QM) * 128 + wm * 64 + i_ * 16 + fr) * 64; \
        a_[i_][0] = *(const v8s*)(ar_ + s0); a_[i_][1] = *(const v8s*)(ar_ + s1); } } \
    if (LB) { _Pragma("unroll") for (int n_ = 0; n_ < 2; ++n_) { \
        const unsigned short* br_ = (Bb) + ((QN) * 128 + wn * 32 + n_ * 16 + fr) * 64; \
        b_[n_][0] = *(const v8s*)(br_ + s0); b_[n_][1] = *(const v8s*)(br_ + s1); } } \
    STAGE_STMT; \
    __builtin_amdgcn_s_setprio(1); \
    _Pragma("unroll") for (int kk_ = 0; kk_ < 2; ++kk_) \
        _Pragma("unroll") for (int i_ = 0; i_ < 4; ++i_) \
            _Pragma("unroll") for (int n_ = 0; n_ < 2; ++n_) \
                acc[(QM) * 4 + i_][(QN) * 2 + n_] = __builtin_amdgcn_mfma_f32_16x16x32_bf16( \
                    a_[i_][kk_], b_[n_][kk_], acc[(QM) * 4 + i_][(QN) * 2 + n_], 0, 0, 0); \
    __builtin_amdgcn_s_setprio(0); \
    __builtin_amdgcn_sched_barrier(0); \
    if (VM4) { asm volatile("s_waitcnt vmcnt(4)" ::: "memory"); } \
    __builtin_amdgcn_s_barrier(); \
    __builtin_amdgcn_sched_barrier(0); \
} while (0)

__global__ __launch_bounds__(512, 2) void gemm1_kernel(
    const unsigned short* __restrict__ xb, const unsigned short* __restrict__ Bpack,
    const float* __restrict__ bias, const int* __restrict__ cnt, const int* __restrict__ bp,
    const int* __restrict__ perm, unsigned short* __restrict__ actP) {
    constexpr int NT = 16;
    int p = blockIdx.x;
    int tm = (p >> 3) & 31;
    int pid = (p & 7) + ((p >> 8) << 3);
    int e = pid >> 4;
    int jb = pid & 15;
    int cn = cnt[e];
    if (tm * 256 >= cn) return;
    int rb = (bp[e] >> 8) + tm;

    __shared__ __align__(16) unsigned short SH[66560];
    unsigned short* As0 = SH;
    unsigned short* As1 = SH + 16384;
    unsigned short* Bs0 = SH + 32768;
    unsigned short* Bs1 = SH + 49152;

    int tid = threadIdx.x, lane = tid & 63, wid = tid >> 6;
    int wm = wid >> 2, wn = wid & 3;
    int fr = lane & 15, fg = lane >> 4;
    int swz = fr & 7;
    int s0 = (fg ^ swz) * 8;
    int s1 = ((4 + fg) ^ swz) * 8;

    int kgs = tid & 7;
    const unsigned short* aptr[2][2];
#pragma unroll
    for (int q = 0; q < 2; ++q)
#pragma unroll
        for (int h = 0; h < 2; ++h) {
            int lr = q * 128 + h * 64 + (tid >> 3);
            int r = ((lr >> 6) & 1) * 128 + ((lr >> 7) & 1) * 64 + (lr & 63);
            int rl = min(tm * 256 + r, cn - 1);
            int tok = perm[e * M_ + rl];
            aptr[q][h] = xb + (size_t)tok * D_ + ((kgs ^ (lr & 7)) << 3);
        }

    const unsigned short* Bsrc = Bpack + (((size_t)(e * 16 + jb) * NT) << 14);

    v4f acc[8][4] = {};
    v8s a_[4][2];
    v8s b_[2][2];

    STA_X(As0, 0, 0); STB_(Bs0, 0, 1); STA_X(As0, 0, 1); STB_(Bs0, 0, 0);
    STA_X(As1, 1, 0); STB_(Bs1, 1, 1);
    asm volatile("s_waitcnt vmcnt(0)" ::: "memory");
    __builtin_amdgcn_s_barrier();
    __builtin_amdgcn_sched_barrier(0);

    for (int i2 = 0; i2 < NT / 2; ++i2) {
        int T1 = 2 * i2 + 1;
        int T2c = min(2 * i2 + 2, NT - 1);
        int T3c = min(2 * i2 + 3, NT - 1);
        PHASE(As0, Bs0, 0, 0, 1, 1, STB_(Bs1, T1, 0), 0);
        PHASE(As0, Bs0, 0, 1, 0, 1, STA_X(As1, T1, 1), 0);
        PHASE(As0, Bs0, 1, 1, 1, 0, STA_X(As0, T2c, 0), 0);
        PHASE(As0, Bs0, 1, 0, 0, 1, STB_(Bs0, T2c, 1), 1);
        PHASE(As1, Bs1, 0, 0, 1, 1, STB_(Bs0, T2c, 0), 0);
        PHASE(As1, Bs1, 0, 1, 0, 1, STA_X(As0, T2c, 1), 0);
        PHASE(As1, Bs1, 1, 1, 1, 0, STA_X(As1, T3c, 0), 0);
        PHASE(As1, Bs1, 1, 0, 0, 1, STB_(Bs1, T3c, 1), 1);
    }
    asm volatile("s_waitcnt vmcnt(0)" ::: "memory");
    __syncthreads();

    // epilogue: silu(a)*b -> LDS [256][136] -> packed actP units
    unsigned short* actl = SH;
    int hl0 = wn * 32 + fr, hl1 = wn * 32 + 16 + fr;
    float ba0 = bias[e * H2_ + jb * 128 + hl0];
    float bb0 = bias[e * H2_ + H_ + jb * 128 + hl0];
    float ba1 = bias[e * H2_ + jb * 128 + hl1];
    float bb1 = bias[e * H2_ + H_ + jb * 128 + hl1];
#pragma unroll
    for (int I = 0; I < 8; ++I) {
        int r0 = wm * 128 + (I >> 2) * 64 + (I & 3) * 16 + fg * 4;
#pragma unroll
        for (int rr = 0; rr < 4; ++rr) {
            float a0 = acc[I][0][rr] + ba0, b0 = acc[I][2][rr] + bb0;
            float a1 = acc[I][1][rr] + ba1, b1 = acc[I][3][rr] + bb1;
            actl[(r0 + rr) * 136 + hl0] = f2b(a0 / (1.f + __expf(-a0)) * b0);
            actl[(r0 + rr) * 136 + hl1] = f2b(a1 / (1.f + __expf(-a1)) * b1);
        }
    }
    __syncthreads();
#pragma unroll
    for (int c8 = 0; c8 < 8; ++c8) {
        int cid = c8 * 512 + tid;
        int t2l = cid >> 11, rem = cid & 2047;
        int q = rem >> 10, s = rem & 1023;
        int lr = q * 128 + (s >> 3);
        int g = (s & 7) ^ (lr & 7);
        int r = ((lr >> 6) & 1) * 128 + (lr >> 7) * 64 + (lr & 63);
        v8s v = *(const v8s*)(actl + r * 136 + t2l * 64 + g * 8);
        *(v8s*)(actP + ((((size_t)rb * 32 + jb * 2 + t2l) * 2 + q) << 13) + s * 8) = v;
    }
}

// ---------- GEMM2: 256x128, 4-phase, triple-buffered B, ONE barrier/phase ----------
#define STAH2(dst, t, q) { const unsigned short* s_ = Asrc + (((size_t)(t) * 2 + (q)) << 13) + tid * 8; \
    GLDS(s_, (dst) + (q) * 8192 + tid * 8); \
    GLDS(s_ + 4096, (dst) + (q) * 8192 + 4096 + tid * 8); }
#define STBH2(dst, t, h) { const unsigned short* s_ = Bsrc + ((size_t)(t) * 8192) + (h) * 4096 + tid * 8; \
    GLDS(s_, (dst) + (h) * 4096 + tid * 8); }

#define PHASE2(Ab, Bp_, QM, LB, STAGE_STMT) do { \
    _Pragma("unroll") for (int i_ = 0; i_ < 4; ++i_) { \
        const unsigned short* ar_ = (Ab) + ((QM) * 128 + wm * 64 + i_ * 16 + fr) * 64; \
        a_[i_][0] = *(const v8s*)(ar_ + s0); a_[i_][1] = *(const v8s*)(ar_ + s1); } \
    if (LB) { _Pragma("unroll") for (int n_ = 0; n_ < 2; ++n_) { \
        const unsigned short* br_ = (Bp_) + (wn * 32 + n_ * 16 + fr) * 64; \
        b_[n_][0] = *(const v8s*)(br_ + s0); b_[n_][1] = *(const v8s*)(br_ + s1); } } \
    STAGE_STMT; \
    __builtin_amdgcn_s_setprio(1); \
    _Pragma("unroll") for (int kk_ = 0; kk_ < 2; ++kk_) \
        _Pragma("unroll") for (int i_ = 0; i_ < 4; ++i_) \
            _Pragma("unroll") for (int n_ = 0; n_ < 2; ++n_) \
                acc[(QM) * 4 + i_][n_] = __builtin_amdgcn_mfma_f32_16x16x32_bf16( \
                    a_[i_][kk_], b_[n_][kk_], acc[(QM) * 4 + i_][n_], 0, 0, 0); \
    __builtin_amdgcn_s_setprio(0); \
    __builtin_amdgcn_sched_barrier(0); \
    asm volatile("s_waitcnt vmcnt(6)" ::: "memory"); \
    __builtin_amdgcn_s_barrier(); \
    __builtin_amdgcn_sched_barrier(0); \
} while (0)

__global__ __launch_bounds__(512, 2) void gemm2_kernel(
    const unsigned short* __restrict__ actP, const unsigned short* __restrict__ W2P,
    const float* __restrict__ bl2, const int* __restrict__ cnt, const int* __restrict__ bp,
    float* __restrict__ y) {
    constexpr int NT = 32;
    int p = blockIdx.x;
    int tm = (p >> 3) & 31;
    int pid = (p & 7) + ((p >> 8) << 3);
    int e = pid >> 3;
    int jb = pid & 7;
    int cn = cnt[e];
    if (tm * 256 >= cn) return;
    int rb = (bp[e] >> 8) + tm;

    __shared__ __align__(16) unsigned short SH[57344];
    unsigned short* As0 = SH;
    unsigned short* As1 = SH + 16384;
    unsigned short* Bb0 = SH + 32768;
    unsigned short* Bb1 = SH + 40960;
    unsigned short* Bb2 = SH + 49152;

    int tid = threadIdx.x, lane = tid & 63, wid = tid >> 6;
    int wm = wid >> 2, wn = wid & 3;
    int fr = lane & 15, fg = lane >> 4;
    int swz = fr & 7;
    int s0 = (fg ^ swz) * 8;
    int s1 = ((4 + fg) ^ swz) * 8;

    const unsigned short* Asrc = actP + ((size_t)rb << 19);
    const unsigned short* Bsrc = W2P + ((size_t)(e * 8 + jb) * 32) * 8192;

    v4f acc[8][2] = {};
    v8s a_[4][2];
    v8s b_[2][2];

    STAH2(As0, 0, 0); STAH2(As0, 0, 1);
    STBH2(Bb0, 0, 0); STBH2(Bb0, 0, 1);
    STAH2(As1, 1, 0);
    STBH2(Bb1, 1, 0); STBH2(Bb1, 1, 1);
    asm volatile("s_waitcnt vmcnt(0)" ::: "memory");
    __builtin_amdgcn_s_barrier();
    __builtin_amdgcn_sched_barrier(0);

    unsigned short* Bc0 = Bb0;
    unsigned short* Bc1 = Bb1;
    unsigned short* Bn = Bb2;
    for (int i2 = 0; i2 < NT / 2; ++i2) {
        int T1 = 2 * i2 + 1;
        int T2 = min(2 * i2 + 2, NT - 1);
        int T3 = min(2 * i2 + 3, NT - 1);
        PHASE2(As0, Bc0, 0, 1, { STAH2(As1, T1, 1); STBH2(Bn, T2, 0); });
        PHASE2(As0, Bc0, 1, 0, { STAH2(As0, T2, 0); STBH2(Bn, T2, 1); });
        PHASE2(As1, Bc1, 0, 1, { STAH2(As0, T2, 1); STBH2(Bc0, T3, 0); });
        PHASE2(As1, Bc1, 1, 0, { STAH2(As1, T3, 0); STBH2(Bc0, T3, 1); });
        unsigned short* oB0 = Bc0;
        Bc0 = Bn; Bn = Bc1; Bc1 = oB0;
    }
    asm volatile("s_waitcnt vmcnt(0)" ::: "memory");
    __syncthreads();

    // epilogue: +bl2 -> LDS f32 [128][132] -> coalesced y rows
    float* yl = (float*)SH;
    int bsr = bp[16 + e];
    float b2_0 = bl2[e * D_ + jb * 128 + wn * 32 + fr];
    float b2_1 = bl2[e * D_ + jb * 128 + wn * 32 + 16 + fr];
#pragma unroll
    for (int wmp = 0; wmp < 2; ++wmp) {
        if (wm == wmp) {
#pragma unroll
            for (int I = 0; I < 8; ++I) {
                int r0 = (I >> 2) * 64 + (I & 3) * 16 + fg * 4;
#pragma unroll
                for (int rr = 0; rr < 4; ++rr) {
                    yl[(r0 + rr) * 132 + wn * 32 + fr] = acc[I][0][rr] + b2_0;
                    yl[(r0 + rr) * 132 + wn * 32 + 16 + fr] = acc[I][1][rr] + b2_1;
                }
            }
        }
        __syncthreads();
#pragma unroll
        for (int f = 0; f < 8; ++f) {
            int fid = f * 512 + tid;
            int row = fid >> 5, c4 = fid & 31;
            int rp = tm * 256 + wmp * 128 + row;
            if (rp < cn) {
                float4 v = *(const float4*)(yl + row * 132 + c4 * 4);
                *(float4*)(y + (size_t)(bsr + rp) * D_ + jb * 128 + c4 * 4) = v;
            }
        }
        __syncthreads();
    }
}

// ---------- combine ----------
__global__ __launch_bounds__(256) void combine_kernel(
    const float* __restrict__ y, const int* __restrict__ slot_idx,
    const float* __restrict__ slot_w, const int* __restrict__ bp,
    float* __restrict__ out) {
    int m = blockIdx.x * 4 + (threadIdx.x >> 6);
    int t2 = threadIdx.x & 63;
    int i0 = slot_idx[m * 2], i1 = slot_idx[m * 2 + 1];
    float w0 = slot_w[m * 2], w1 = slot_w[m * 2 + 1];
    const float4* y0 = (const float4*)(y + (size_t)(bp[16 + (i0 >> 13)] + (i0 & (M_ - 1))) * D_);
    const float4* y1 = (const float4*)(y + (size_t)(bp[16 + (i1 >> 13)] + (i1 & (M_ - 1))) * D_);
    float4* o = (float4*)(out + (size_t)m * D_);
#pragma unroll
    for (int k = 0; k < 4; ++k) {
        int idx = k * 64 + t2;
        float4 a = y0[idx], b = y1[idx];
        float4 r;
        r.x = w0 * a.x + w1 * b.x;
        r.y = w0 * a.y + w1 * b.y;
        r.z = w0 * a.z + w1 * b.z;
        r.w = w0 * a.w + w1 * b.w;
        o[idx] = r;
    }
}

__global__ void ws_fail_kernel(float* __restrict__ out) {
    if (threadIdx.x == 0 && blockIdx.x == 0) out[0] = 1e30f;
}

extern "C" void kernel_launch(void* const* d_in, const int* in_sizes, int n_in,
                              void* d_out, int out_size, void* d_ws, size_t ws_size,
                              hipStream_t stream) {
    const float* x = (const float*)d_in[0];
    const float* Wr = (const float*)d_in[1];
    const float* br = (const float*)d_in[2];
    const float* Wl1 = (const float*)d_in[3];
    const float* bl1 = (const float*)d_in[4];
    const float* Wl2 = (const float*)d_in[5];
    const float* bl2 = (const float*)d_in[6];
    const float* biases = (const float*)d_in[7];
    float* out = (float*)d_out;

    char* ws = (char*)d_ws;
    size_t off = 0;
    auto alloc = [&](size_t bytes) {
        char* p = ws + off;
        off += (bytes + 255) & ~(size_t)255;
        return p;
    };
    unsigned short* W1P = (unsigned short*)alloc((size_t)NE * 16 * 16 * 2 * 8192 * 2);  // 64 MB
    unsigned short* W2P = (unsigned short*)alloc((size_t)NE * 8 * 32 * 8192 * 2);       // 32 MB
    unsigned short* xb = (unsigned short*)alloc((size_t)M_ * D_ * 2);                   // 16 MB
    unsigned short* actP = (unsigned short*)alloc((size_t)RBMAX * 32 * 2 * 8192 * 2);   // 72 MB
    int* perm = (int*)alloc((size_t)NE * M_ * 4);
    int* slot_idx = (int*)alloc((size_t)M_ * 2 * 4);
    float* slot_w = (float*)alloc((size_t)M_ * 2 * 4);
    int* pick = (int*)alloc((size_t)M_ * 4);
    int* blkcnt = (int*)alloc(64 * NE * 4);
    int* blkoff = (int*)alloc(64 * NE * 4);
    int* cnt = (int*)alloc(256);
    int* bp = (int*)alloc(256);
    float* y = (float*)W1P;  // W1P dead after gemm1
    if (ws_size < off) {
        ws_fail_kernel<<<1, 64, 0, stream>>>(out);
        return;
    }

    pack_w1_kernel<<<dim3(16, 16, NE), 256, 0, stream>>>(Wl1, W1P);
    pack_w2_kernel<<<dim3(8, 32, NE), 256, 0, stream>>>(Wl2, W2P);
    router_score_kernel<<<M_ / 4, 256, 0, stream>>>(x, Wr, br, biases, pick, slot_w, xb);
    hist_kernel<<<64, 256, 0, stream>>>(pick, blkcnt);
    scan_kernel<<<1, 64, 0, stream>>>(blkcnt, blkoff, cnt, bp);
    scatter_kernel<<<64, 256, 0, stream>>>(pick, blkoff, perm, slot_idx);
    gemm1_kernel<<<32 * 16 * NE, 512, 0, stream>>>(xb, W1P, bl1, cnt, bp, perm, actP);
    gemm2_kernel<<<32 * 8 * NE, 512, 0, stream>>>(actP, W2P, bl2, cnt, bp, y);
    combine_kernel<<<M_ / 4, 256, 0, stream>>>(y, slot_idx, slot_w, bp, out);
}